// Round 5
// baseline (351.733 us; speedup 1.0000x reference)
//
#include <hip/hip_runtime.h>

#define DIM 512
#define QKD 128
#define BATCH 4
#define SEQ 4096

typedef __attribute__((ext_vector_type(8)))  _Float16 f16x8;
typedef __attribute__((ext_vector_type(4)))  _Float16 f16x4;
typedef __attribute__((ext_vector_type(4)))  float    f32x4;
typedef __attribute__((ext_vector_type(16))) float    f32x16;

// ---------------------------------------------------------------------------
// Prep: w_qk fp32 -> fp16, permuted to MFMA-fragment order for kernel A:
//   w16f[kc][nb][lane][j] = w[e = nb*16 + (lane&15)][d = kc*32 + (lane>>4)*8 + j]
// ---------------------------------------------------------------------------
__global__ __launch_bounds__(256) void wcvt_kernel(
    const float* __restrict__ w, _Float16* __restrict__ w16f)
{
    const int t    = blockIdx.x * 256 + threadIdx.x;   // 0..8191
    const int lane = t & 63;
    const int nb   = (t >> 6) & 7;
    const int kc   = t >> 9;                           // 0..15
    const int e    = nb * 16 + (lane & 15);
    const int d0   = kc * 32 + (lane >> 4) * 8;
    const float4* src = (const float4*)(w + (size_t)e * DIM + d0);
    const float4 a = src[0], b = src[1];
    f16x8 o;
    o[0] = (_Float16)a.x; o[1] = (_Float16)a.y;
    o[2] = (_Float16)a.z; o[3] = (_Float16)a.w;
    o[4] = (_Float16)b.x; o[5] = (_Float16)b.y;
    o[6] = (_Float16)b.z; o[7] = (_Float16)b.w;
    *(f16x8*)(w16f + (size_t)t * 8) = o;
}

// ---------------------------------------------------------------------------
// Kernel A: LayerNorm + Linear(512->128) + SiLU + OffsetScale -> q,k (fp16)
// 16 rows/block, 1024 blocks (4 waves/SIMD); all x-loads hoisted; epilogue
// routed through LDS for coalesced f16x8 stores. Outputs in MFMA-fragment
// order: off = g*4096 + (e>>3)*256 + (row%32)*8 + (e&7).
// Folds 1/sqrt(4096) as 1/8 into both q and k.
// ---------------------------------------------------------------------------
__global__ __launch_bounds__(256, 4) void ln_qk_kernel(
    const float* __restrict__ x,
    const float* __restrict__ ln_w,
    const float* __restrict__ ln_b,
    const _Float16* __restrict__ w16f,
    const float* __restrict__ b_qk,
    const float* __restrict__ gamma,
    const float* __restrict__ beta,
    _Float16* __restrict__ q_h,
    _Float16* __restrict__ k_h)
{
    __shared__ _Float16 As[16][520];    // LN output, 16B-aligned rows
    __shared__ _Float16 Qs[16][136];    // epilogue staging (136: 16B-aligned rows)
    __shared__ _Float16 Ks[16][136];
    const int tid  = threadIdx.x;
    const int wave = tid >> 6;
    const int lane = tid & 63;
    const int row0 = blockIdx.x * 16;

    // per-lane LN params for d = lane*8 .. +7
    float lw[8], lb[8];
    {
        const float4* w4 = (const float4*)ln_w;
        const float4* b4 = (const float4*)ln_b;
        float4 w0 = w4[lane * 2], w1 = w4[lane * 2 + 1];
        float4 b0 = b4[lane * 2], b1 = b4[lane * 2 + 1];
        lw[0]=w0.x; lw[1]=w0.y; lw[2]=w0.z; lw[3]=w0.w;
        lw[4]=w1.x; lw[5]=w1.y; lw[6]=w1.z; lw[7]=w1.w;
        lb[0]=b0.x; lb[1]=b0.y; lb[2]=b0.z; lb[3]=b0.w;
        lb[4]=b1.x; lb[5]=b1.y; lb[6]=b1.z; lb[7]=b1.w;
    }

    // LN: each wave handles 4 rows; hoist ALL loads first (8 in flight/lane)
    float4 xa[4], xb[4];
#pragma unroll
    for (int rr = 0; rr < 4; ++rr) {
        const float4* xr = (const float4*)(x + (size_t)(row0 + wave * 4 + rr) * DIM);
        xa[rr] = xr[lane * 2];
        xb[rr] = xr[lane * 2 + 1];
    }
#pragma unroll
    for (int rr = 0; rr < 4; ++rr) {
        float xv[8] = {xa[rr].x, xa[rr].y, xa[rr].z, xa[rr].w,
                       xb[rr].x, xb[rr].y, xb[rr].z, xb[rr].w};
        float s = 0.f, s2 = 0.f;
#pragma unroll
        for (int j = 0; j < 8; ++j) { s += xv[j]; s2 = fmaf(xv[j], xv[j], s2); }
#pragma unroll
        for (int off = 32; off > 0; off >>= 1) {
            s  += __shfl_xor(s,  off);
            s2 += __shfl_xor(s2, off);
        }
        const float mu   = s * (1.f / DIM);
        const float var  = s2 * (1.f / DIM) - mu * mu;
        const float rstd = rsqrtf(var + 1e-5f);
        f16x8 hh;
#pragma unroll
        for (int j = 0; j < 8; ++j)
            hh[j] = (_Float16)(fmaf((xv[j] - mu) * rstd, lw[j], lb[j]));
        *(f16x8*)&As[wave * 4 + rr][lane * 8] = hh;
    }
    __syncthreads();

    // GEMM: M=16 (one m-tile), N=128 (each wave owns 2 n-blocks of 16)
    const int lcol = lane & 15;
    const int quad = lane >> 4;

    f32x4 acc[2];
    acc[0] = (f32x4){0.f, 0.f, 0.f, 0.f};
    acc[1] = (f32x4){0.f, 0.f, 0.f, 0.f};

    const _Float16* arow = &As[lcol][quad * 8];
#pragma unroll 4
    for (int kc = 0; kc < 16; ++kc) {
        const f16x8 af = *(const f16x8*)(arow + kc * 32);
#pragma unroll
        for (int nt = 0; nt < 2; ++nt) {
            const f16x8 bfr = *(const f16x8*)(
                w16f + (size_t)((kc * 8 + wave * 2 + nt) * 64 + lane) * 8);
            acc[nt] = __builtin_amdgcn_mfma_f32_16x16x32_f16(af, bfr, acc[nt], 0, 0, 0);
        }
    }

    // epilogue: bias + SiLU + offset-scale (x 1/8) -> LDS staging
#pragma unroll
    for (int nt = 0; nt < 2; ++nt) {
        const int e = (wave * 2 + nt) * 16 + lcol;
        const float bq  = b_qk[e];
        const float g0  = gamma[e]       * 0.125f;
        const float g1  = gamma[QKD + e] * 0.125f;
        const float be0 = beta[e]        * 0.125f;
        const float be1 = beta[QKD + e]  * 0.125f;
#pragma unroll
        for (int reg = 0; reg < 4; ++reg) {
            const int m  = quad * 4 + reg;      // local row 0..15
            const float v   = acc[nt][reg] + bq;
            const float sil = v / (1.f + __expf(-v));
            Qs[m][e] = (_Float16)fmaf(sil, g0, be0);
            Ks[m][e] = (_Float16)fmaf(sil, g1, be1);
        }
    }
    __syncthreads();

    // coalesced store: thread t -> (mm = t&15, eh = t>>4); fragment layout has
    // j innermost so [base..base+7] is contiguous; 16-lane groups form 256-B runs
    {
        const int mm = tid & 15, eh = tid >> 4;
        const f16x8 qv = *(const f16x8*)&Qs[mm][eh * 8];
        const f16x8 kv = *(const f16x8*)&Ks[mm][eh * 8];
        const size_t base = ((size_t)(blockIdx.x >> 1)) * 4096
                          + (size_t)eh * 256 + (blockIdx.x & 1) * 128 + mm * 8;
        *(f16x8*)(q_h + base) = qv;
        *(f16x8*)(k_h + base) = kv;
    }
}

// ---------------------------------------------------------------------------
// Kernel B (fused): per block 32 rows x ALL 4096 cols; pass 1 accumulates
// rowsums of relu(sim)^2 (reduced in LDS), pass 2 recomputes (identical MFMA
// order -> self-consistent) and stores normalized output.
// R5: register-neutral SOFTWARE PIPELINE on the k-fragment buffer: rotate
// bf[8] in halves so every k load has ~100-200 cyc of same-wave MFMA/VALU
// between issue and consume (was: load 8, consume immediately -> full L2
// latency exposed; TLP capped at 4 waves/SIMD by the 112-VGPR live set).
// Pass-2 ct0 loads issue before the rowsum reduce/barrier for the same reason.
// 512 blocks x 512 thr, all co-resident. XCD swizzle pins one batch per XCD L2.
// ---------------------------------------------------------------------------
__global__ __launch_bounds__(512, 4) void attn_kernel(
    const _Float16* __restrict__ q_h,
    const _Float16* __restrict__ k_h,
    float* __restrict__ out)
{
    const int l     = blockIdx.x;                    // 0..511
    const int batch = (l & 7) >> 1;
    const int tile  = ((l >> 3) << 1) | (l & 1);     // 0..127

    const int wid  = threadIdx.x >> 6;               // 0..7 col-wave
    const int lane = threadIdx.x & 63;
    const int n    = lane & 31;
    const int h    = lane >> 5;

    // q fragments: contiguous 4 KB block for this 32-row tile
    const _Float16* qb = q_h + (size_t)(batch * 128 + tile) * 4096;
    f16x8 aq[8];
#pragma unroll
    for (int kc = 0; kc < 8; ++kc)
        aq[kc] = *(const f16x8*)(qb + kc * 512 + lane * 8);

    // k col-block g = ct*8 + wid  (col = ct*256 + wid*32 + n); 32768 halfs/ct
    const _Float16* kb0 = k_h + (size_t)(batch * 128 + wid) * 4096 + lane * 8;

    __shared__ float partial[8][32];
    __shared__ float srow_s[32];

    float rs[16];
#pragma unroll
    for (int r = 0; r < 16; ++r) rs[r] = 0.f;

    f16x8 bf[8];
#pragma unroll
    for (int kc = 0; kc < 8; ++kc)
        bf[kc] = *(const f16x8*)(kb0 + kc * 512);

    // ---- pass 1: row sums of relu(sim)^2, pipelined ----
    for (int ct = 0; ct < 15; ++ct) {
        const _Float16* nb = kb0 + (size_t)(ct + 1) * 32768;
        f32x16 acc;
#pragma unroll
        for (int r = 0; r < 16; ++r) acc[r] = 0.f;

        __builtin_amdgcn_s_setprio(1);
#pragma unroll
        for (int kc = 0; kc < 4; ++kc)
            acc = __builtin_amdgcn_mfma_f32_32x32x16_f16(aq[kc], bf[kc], acc, 0, 0, 0);
        __builtin_amdgcn_s_setprio(0);
#pragma unroll
        for (int kc = 0; kc < 4; ++kc)
            bf[kc] = *(const f16x8*)(nb + kc * 512);     // prefetch ct+1, kc 0-3

        __builtin_amdgcn_s_setprio(1);
#pragma unroll
        for (int kc = 4; kc < 8; ++kc)
            acc = __builtin_amdgcn_mfma_f32_32x32x16_f16(aq[kc], bf[kc], acc, 0, 0, 0);
        __builtin_amdgcn_s_setprio(0);
#pragma unroll
        for (int kc = 4; kc < 8; ++kc)
            bf[kc] = *(const f16x8*)(nb + kc * 512);     // prefetch ct+1, kc 4-7

#pragma unroll
        for (int r = 0; r < 16; ++r) {
            const float t = fmaxf(acc[r], 0.f);
            rs[r] = fmaf(t, t, rs[r]);
        }
    }
    {   // ct = 15, no prefetch
        f32x16 acc;
#pragma unroll
        for (int r = 0; r < 16; ++r) acc[r] = 0.f;
        __builtin_amdgcn_s_setprio(1);
#pragma unroll
        for (int kc = 0; kc < 8; ++kc)
            acc = __builtin_amdgcn_mfma_f32_32x32x16_f16(aq[kc], bf[kc], acc, 0, 0, 0);
        __builtin_amdgcn_s_setprio(0);
#pragma unroll
        for (int r = 0; r < 16; ++r) {
            const float t = fmaxf(acc[r], 0.f);
            rs[r] = fmaf(t, t, rs[r]);
        }
    }

    // issue pass-2 ct0 loads now; the reduce + barrier below covers the latency
#pragma unroll
    for (int kc = 0; kc < 8; ++kc)
        bf[kc] = *(const f16x8*)(kb0 + kc * 512);

    // reduce across the 32 n-lanes, then across the 8 col-waves (in LDS)
#pragma unroll
    for (int r = 0; r < 16; ++r) {
        float v = rs[r];
        v += __shfl_xor(v, 1);
        v += __shfl_xor(v, 2);
        v += __shfl_xor(v, 4);
        v += __shfl_xor(v, 8);
        v += __shfl_xor(v, 16);
        if (n == 0) partial[wid][(r & 3) + 8 * (r >> 2) + 4 * h] = v;
    }
    __syncthreads();
    if (threadIdx.x < 32) {
        float t = 0.f;
#pragma unroll
        for (int w = 0; w < 8; ++w) t += partial[w][threadIdx.x];
        srow_s[threadIdx.x] = rsqrtf(t + 1e-6f);  // out = (v*srow)^2 = v^2/(sum+1e-6)
    }
    __syncthreads();

    float srow[16];
#pragma unroll
    for (int r = 0; r < 16; ++r)
        srow[r] = srow_s[(r & 3) + 8 * (r >> 2) + 4 * h];

    // ---- pass 2: recompute (identical order) + normalize + nt store, pipelined ----
    float* ob = out + ((size_t)batch * SEQ + tile * 32) * SEQ;

    for (int ct = 0; ct < 15; ++ct) {
        const _Float16* nb = kb0 + (size_t)(ct + 1) * 32768;
        f32x16 acc;
#pragma unroll
        for (int r = 0; r < 16; ++r) acc[r] = 0.f;

        __builtin_amdgcn_s_setprio(1);
#pragma unroll
        for (int kc = 0; kc < 4; ++kc)
            acc = __builtin_amdgcn_mfma_f32_32x32x16_f16(aq[kc], bf[kc], acc, 0, 0, 0);
        __builtin_amdgcn_s_setprio(0);
#pragma unroll
        for (int kc = 0; kc < 4; ++kc)
            bf[kc] = *(const f16x8*)(nb + kc * 512);

        __builtin_amdgcn_s_setprio(1);
#pragma unroll
        for (int kc = 4; kc < 8; ++kc)
            acc = __builtin_amdgcn_mfma_f32_32x32x16_f16(aq[kc], bf[kc], acc, 0, 0, 0);
        __builtin_amdgcn_s_setprio(0);
#pragma unroll
        for (int kc = 4; kc < 8; ++kc)
            bf[kc] = *(const f16x8*)(nb + kc * 512);

        const int col = ct * 256 + wid * 32 + n;
#pragma unroll
        for (int r = 0; r < 16; ++r) {
            const float t   = fmaxf(acc[r], 0.f) * srow[r];
            const int   row = (r & 3) + 8 * (r >> 2) + 4 * h;
            __builtin_nontemporal_store(t * t, ob + (size_t)row * SEQ + col);
        }
    }
    {   // ct = 15, no prefetch
        f32x16 acc;
#pragma unroll
        for (int r = 0; r < 16; ++r) acc[r] = 0.f;
        __builtin_amdgcn_s_setprio(1);
#pragma unroll
        for (int kc = 0; kc < 8; ++kc)
            acc = __builtin_amdgcn_mfma_f32_32x32x16_f16(aq[kc], bf[kc], acc, 0, 0, 0);
        __builtin_amdgcn_s_setprio(0);

        const int col = 15 * 256 + wid * 32 + n;
#pragma unroll
        for (int r = 0; r < 16; ++r) {
            const float t   = fmaxf(acc[r], 0.f) * srow[r];
            const int   row = (r & 3) + 8 * (r >> 2) + 4 * h;
            __builtin_nontemporal_store(t * t, ob + (size_t)row * SEQ + col);
        }
    }
}

extern "C" void kernel_launch(void* const* d_in, const int* in_sizes, int n_in,
                              void* d_out, int out_size, void* d_ws, size_t ws_size,
                              hipStream_t stream) {
    const float* x     = (const float*)d_in[0];
    const float* ln_w  = (const float*)d_in[1];
    const float* ln_b  = (const float*)d_in[2];
    const float* w_qk  = (const float*)d_in[3];
    const float* b_qk  = (const float*)d_in[4];
    const float* gamma = (const float*)d_in[5];
    const float* beta  = (const float*)d_in[6];
    float* out = (float*)d_out;

    _Float16* q_h  = (_Float16*)d_ws;                           // 4 MB
    _Float16* k_h  = q_h + (size_t)BATCH * SEQ * QKD;           // 4 MB
    _Float16* w16f = k_h + (size_t)BATCH * SEQ * QKD;           // 128 KB

    hipLaunchKernelGGL(wcvt_kernel, dim3(32), dim3(256), 0, stream, w_qk, w16f);
    hipLaunchKernelGGL(ln_qk_kernel, dim3((BATCH * SEQ) / 16), dim3(256), 0, stream,
                       x, ln_w, ln_b, w16f, b_qk, gamma, beta, q_h, k_h);
    hipLaunchKernelGGL(attn_kernel, dim3(BATCH * (SEQ / 32)), dim3(512), 0, stream,
                       q_h, k_h, out);
}

// Round 6
// 329.397 us; speedup vs baseline: 1.0678x; 1.0678x over previous
//
#include <hip/hip_runtime.h>

#define DIM 512
#define QKD 128
#define BATCH 4
#define SEQ 4096

typedef __attribute__((ext_vector_type(8)))  _Float16 f16x8;
typedef __attribute__((ext_vector_type(4)))  _Float16 f16x4;
typedef __attribute__((ext_vector_type(4)))  float    f32x4;
typedef __attribute__((ext_vector_type(16))) float    f32x16;

// ---------------------------------------------------------------------------
// Prep: w_qk fp32 -> fp16, permuted to MFMA-fragment order for kernel A:
//   w16f[kc][nb][lane][j] = w[e = nb*16 + (lane&15)][d = kc*32 + (lane>>4)*8 + j]
// ---------------------------------------------------------------------------
__global__ __launch_bounds__(256) void wcvt_kernel(
    const float* __restrict__ w, _Float16* __restrict__ w16f)
{
    const int t    = blockIdx.x * 256 + threadIdx.x;   // 0..8191
    const int lane = t & 63;
    const int nb   = (t >> 6) & 7;
    const int kc   = t >> 9;                           // 0..15
    const int e    = nb * 16 + (lane & 15);
    const int d0   = kc * 32 + (lane >> 4) * 8;
    const float4* src = (const float4*)(w + (size_t)e * DIM + d0);
    const float4 a = src[0], b = src[1];
    f16x8 o;
    o[0] = (_Float16)a.x; o[1] = (_Float16)a.y;
    o[2] = (_Float16)a.z; o[3] = (_Float16)a.w;
    o[4] = (_Float16)b.x; o[5] = (_Float16)b.y;
    o[6] = (_Float16)b.z; o[7] = (_Float16)b.w;
    *(f16x8*)(w16f + (size_t)t * 8) = o;
}

// ---------------------------------------------------------------------------
// Kernel A: LayerNorm + Linear(512->128) + SiLU + OffsetScale -> q,k (fp16)
// 16 rows/block, 1024 blocks (4 waves/SIMD); all x-loads hoisted; epilogue
// routed through LDS for coalesced f16x8 stores. Outputs in MFMA-fragment
// order: off = g*4096 + (e>>3)*256 + (row%32)*8 + (e&7).
// Folds 1/sqrt(4096) as 1/8 into both q and k.
// ---------------------------------------------------------------------------
__global__ __launch_bounds__(256, 4) void ln_qk_kernel(
    const float* __restrict__ x,
    const float* __restrict__ ln_w,
    const float* __restrict__ ln_b,
    const _Float16* __restrict__ w16f,
    const float* __restrict__ b_qk,
    const float* __restrict__ gamma,
    const float* __restrict__ beta,
    _Float16* __restrict__ q_h,
    _Float16* __restrict__ k_h)
{
    __shared__ _Float16 As[16][520];    // LN output, 16B-aligned rows
    __shared__ _Float16 Qs[16][136];    // epilogue staging (136: 16B-aligned rows)
    __shared__ _Float16 Ks[16][136];
    const int tid  = threadIdx.x;
    const int wave = tid >> 6;
    const int lane = tid & 63;
    const int row0 = blockIdx.x * 16;

    // per-lane LN params for d = lane*8 .. +7
    float lw[8], lb[8];
    {
        const float4* w4 = (const float4*)ln_w;
        const float4* b4 = (const float4*)ln_b;
        float4 w0 = w4[lane * 2], w1 = w4[lane * 2 + 1];
        float4 b0 = b4[lane * 2], b1 = b4[lane * 2 + 1];
        lw[0]=w0.x; lw[1]=w0.y; lw[2]=w0.z; lw[3]=w0.w;
        lw[4]=w1.x; lw[5]=w1.y; lw[6]=w1.z; lw[7]=w1.w;
        lb[0]=b0.x; lb[1]=b0.y; lb[2]=b0.z; lb[3]=b0.w;
        lb[4]=b1.x; lb[5]=b1.y; lb[6]=b1.z; lb[7]=b1.w;
    }

    // LN: each wave handles 4 rows; hoist ALL loads first (8 in flight/lane)
    float4 xa[4], xb[4];
#pragma unroll
    for (int rr = 0; rr < 4; ++rr) {
        const float4* xr = (const float4*)(x + (size_t)(row0 + wave * 4 + rr) * DIM);
        xa[rr] = xr[lane * 2];
        xb[rr] = xr[lane * 2 + 1];
    }
#pragma unroll
    for (int rr = 0; rr < 4; ++rr) {
        float xv[8] = {xa[rr].x, xa[rr].y, xa[rr].z, xa[rr].w,
                       xb[rr].x, xb[rr].y, xb[rr].z, xb[rr].w};
        float s = 0.f, s2 = 0.f;
#pragma unroll
        for (int j = 0; j < 8; ++j) { s += xv[j]; s2 = fmaf(xv[j], xv[j], s2); }
#pragma unroll
        for (int off = 32; off > 0; off >>= 1) {
            s  += __shfl_xor(s,  off);
            s2 += __shfl_xor(s2, off);
        }
        const float mu   = s * (1.f / DIM);
        const float var  = s2 * (1.f / DIM) - mu * mu;
        const float rstd = rsqrtf(var + 1e-5f);
        f16x8 hh;
#pragma unroll
        for (int j = 0; j < 8; ++j)
            hh[j] = (_Float16)(fmaf((xv[j] - mu) * rstd, lw[j], lb[j]));
        *(f16x8*)&As[wave * 4 + rr][lane * 8] = hh;
    }
    __syncthreads();

    // GEMM: M=16 (one m-tile), N=128 (each wave owns 2 n-blocks of 16)
    const int lcol = lane & 15;
    const int quad = lane >> 4;

    f32x4 acc[2];
    acc[0] = (f32x4){0.f, 0.f, 0.f, 0.f};
    acc[1] = (f32x4){0.f, 0.f, 0.f, 0.f};

    const _Float16* arow = &As[lcol][quad * 8];
#pragma unroll 4
    for (int kc = 0; kc < 16; ++kc) {
        const f16x8 af = *(const f16x8*)(arow + kc * 32);
#pragma unroll
        for (int nt = 0; nt < 2; ++nt) {
            const f16x8 bfr = *(const f16x8*)(
                w16f + (size_t)((kc * 8 + wave * 2 + nt) * 64 + lane) * 8);
            acc[nt] = __builtin_amdgcn_mfma_f32_16x16x32_f16(af, bfr, acc[nt], 0, 0, 0);
        }
    }

    // epilogue: bias + SiLU + offset-scale (x 1/8) -> LDS staging
#pragma unroll
    for (int nt = 0; nt < 2; ++nt) {
        const int e = (wave * 2 + nt) * 16 + lcol;
        const float bq  = b_qk[e];
        const float g0  = gamma[e]       * 0.125f;
        const float g1  = gamma[QKD + e] * 0.125f;
        const float be0 = beta[e]        * 0.125f;
        const float be1 = beta[QKD + e]  * 0.125f;
#pragma unroll
        for (int reg = 0; reg < 4; ++reg) {
            const int m  = quad * 4 + reg;      // local row 0..15
            const float v   = acc[nt][reg] + bq;
            const float sil = v / (1.f + __expf(-v));
            Qs[m][e] = (_Float16)fmaf(sil, g0, be0);
            Ks[m][e] = (_Float16)fmaf(sil, g1, be1);
        }
    }
    __syncthreads();

    // coalesced store: thread t -> (mm = t&15, eh = t>>4); fragment layout has
    // j innermost so [base..base+7] is contiguous; 16-lane groups form 256-B runs
    {
        const int mm = tid & 15, eh = tid >> 4;
        const f16x8 qv = *(const f16x8*)&Qs[mm][eh * 8];
        const f16x8 kv = *(const f16x8*)&Ks[mm][eh * 8];
        const size_t base = ((size_t)(blockIdx.x >> 1)) * 4096
                          + (size_t)eh * 256 + (blockIdx.x & 1) * 128 + mm * 8;
        *(f16x8*)(q_h + base) = qv;
        *(f16x8*)(k_h + base) = kv;
    }
}

// ---------------------------------------------------------------------------
// Kernel B (fused): per block 32 rows x ALL 4096 cols; pass 1 accumulates
// rowsums of relu(sim)^2 (reduced in LDS), pass 2 recomputes (identical MFMA
// order -> self-consistent) and stores normalized output.
// R6: REVERTED to the R4 structure (measured 329 us). R5's manual
// half-rotated prefetch pipeline regressed +23 us: it forced register reuse
// on bf[], pinning the schedule and SHRINKING the load->use distance vs the
// compiler's own unroll-2 double-buffering (m141-class failure). Do not
// hand-schedule this loop; the `#pragma unroll 2` form is the best observed.
// 512 blocks x 512 thr, all co-resident. XCD swizzle pins one batch per XCD L2.
// ---------------------------------------------------------------------------
__global__ __launch_bounds__(512, 4) void attn_kernel(
    const _Float16* __restrict__ q_h,
    const _Float16* __restrict__ k_h,
    float* __restrict__ out)
{
    const int l     = blockIdx.x;                    // 0..511
    const int batch = (l & 7) >> 1;
    const int tile  = ((l >> 3) << 1) | (l & 1);     // 0..127

    const int wid  = threadIdx.x >> 6;               // 0..7 col-wave
    const int lane = threadIdx.x & 63;
    const int n    = lane & 31;
    const int h    = lane >> 5;

    // q fragments: contiguous 4 KB block for this 32-row tile
    const _Float16* qb = q_h + (size_t)(batch * 128 + tile) * 4096;
    f16x8 aq[8];
#pragma unroll
    for (int kc = 0; kc < 8; ++kc)
        aq[kc] = *(const f16x8*)(qb + kc * 512 + lane * 8);

    // k col-block g = ct*8 + wid  (col = ct*256 + wid*32 + n)
    const _Float16* kb0 = k_h + (size_t)(batch * 128 + wid) * 4096 + lane * 8;

    __shared__ float partial[8][32];
    __shared__ float srow_s[32];

    float rs[16];
#pragma unroll
    for (int r = 0; r < 16; ++r) rs[r] = 0.f;

    // ---- pass 1: row sums of relu(sim)^2 ----
#pragma unroll 2
    for (int ct = 0; ct < 16; ++ct) {
        const _Float16* cb = kb0 + (size_t)(ct * 8) * 4096;
        f16x8 bf[8];
#pragma unroll
        for (int kc = 0; kc < 8; ++kc) bf[kc] = *(const f16x8*)(cb + kc * 512);

        f32x16 acc;
#pragma unroll
        for (int r = 0; r < 16; ++r) acc[r] = 0.f;
        __builtin_amdgcn_s_setprio(1);
#pragma unroll
        for (int kc = 0; kc < 8; ++kc)
            acc = __builtin_amdgcn_mfma_f32_32x32x16_f16(aq[kc], bf[kc], acc, 0, 0, 0);
        __builtin_amdgcn_s_setprio(0);
#pragma unroll
        for (int r = 0; r < 16; ++r) {
            const float t = fmaxf(acc[r], 0.f);
            rs[r] = fmaf(t, t, rs[r]);
        }
    }

    // reduce across the 32 n-lanes, then across the 8 col-waves (in LDS)
#pragma unroll
    for (int r = 0; r < 16; ++r) {
        float v = rs[r];
        v += __shfl_xor(v, 1);
        v += __shfl_xor(v, 2);
        v += __shfl_xor(v, 4);
        v += __shfl_xor(v, 8);
        v += __shfl_xor(v, 16);
        if (n == 0) partial[wid][(r & 3) + 8 * (r >> 2) + 4 * h] = v;
    }
    __syncthreads();
    if (threadIdx.x < 32) {
        float t = 0.f;
#pragma unroll
        for (int w = 0; w < 8; ++w) t += partial[w][threadIdx.x];
        srow_s[threadIdx.x] = rsqrtf(t + 1e-6f);  // out = (v*srow)^2 = v^2/(sum+1e-6)
    }
    __syncthreads();

    float srow[16];
#pragma unroll
    for (int r = 0; r < 16; ++r)
        srow[r] = srow_s[(r & 3) + 8 * (r >> 2) + 4 * h];

    // ---- pass 2: recompute (identical order) + normalize + nontemporal store ----
    float* ob = out + ((size_t)batch * SEQ + tile * 32) * SEQ;

#pragma unroll 2
    for (int ct = 0; ct < 16; ++ct) {
        const _Float16* cb = kb0 + (size_t)(ct * 8) * 4096;
        f16x8 bf[8];
#pragma unroll
        for (int kc = 0; kc < 8; ++kc) bf[kc] = *(const f16x8*)(cb + kc * 512);

        f32x16 acc;
#pragma unroll
        for (int r = 0; r < 16; ++r) acc[r] = 0.f;
        __builtin_amdgcn_s_setprio(1);
#pragma unroll
        for (int kc = 0; kc < 8; ++kc)
            acc = __builtin_amdgcn_mfma_f32_32x32x16_f16(aq[kc], bf[kc], acc, 0, 0, 0);
        __builtin_amdgcn_s_setprio(0);

        const int col = ct * 256 + wid * 32 + n;
#pragma unroll
        for (int r = 0; r < 16; ++r) {
            const float t   = fmaxf(acc[r], 0.f) * srow[r];
            const int   row = (r & 3) + 8 * (r >> 2) + 4 * h;
            __builtin_nontemporal_store(t * t, ob + (size_t)row * SEQ + col);
        }
    }
}

extern "C" void kernel_launch(void* const* d_in, const int* in_sizes, int n_in,
                              void* d_out, int out_size, void* d_ws, size_t ws_size,
                              hipStream_t stream) {
    const float* x     = (const float*)d_in[0];
    const float* ln_w  = (const float*)d_in[1];
    const float* ln_b  = (const float*)d_in[2];
    const float* w_qk  = (const float*)d_in[3];
    const float* b_qk  = (const float*)d_in[4];
    const float* gamma = (const float*)d_in[5];
    const float* beta  = (const float*)d_in[6];
    float* out = (float*)d_out;

    _Float16* q_h  = (_Float16*)d_ws;                           // 4 MB
    _Float16* k_h  = q_h + (size_t)BATCH * SEQ * QKD;           // 4 MB
    _Float16* w16f = k_h + (size_t)BATCH * SEQ * QKD;           // 128 KB

    hipLaunchKernelGGL(wcvt_kernel, dim3(32), dim3(256), 0, stream, w_qk, w16f);
    hipLaunchKernelGGL(ln_qk_kernel, dim3((BATCH * SEQ) / 16), dim3(256), 0, stream,
                       x, ln_w, ln_b, w16f, b_qk, gamma, beta, q_h, k_h);
    hipLaunchKernelGGL(attn_kernel, dim3(BATCH * (SEQ / 32)), dim3(512), 0, stream,
                       q_h, k_h, out);
}